// Round 16
// baseline (5650.349 us; speedup 1.0000x reference)
//
#include <hip/hip_runtime.h>

// y[m][n] = sum_k x[m][k] * (w[n][k]*scale[n]) + bias[n]
// M=8192, N=11008, K=4096. fp32 in/out, bf16 MFMA compute.
//
// R13: 2-blocks-per-CU TLP experiment. 256x256 tile, 8 waves (2Mx4N),
// BK=32, simple 2-dbuf LDS = 64 KB (2 blocks/CU, 16 waves/CU). Fine
// 2-phase K-tile: {8 ds_reads + stageA(t+1) -> BAR -> 16 MFMA -> BAR},
// {4 ds_reads + stageB(t+1) -> BAR -> 16 MFMA -> vmcnt(0) -> BAR}.
// Drain-to-0 per K-tile is covered by the co-resident block (m114 pipe
// co-scheduling). Read-side XOR swizzle (R2-verified 0 conflicts at this
// exact 64B-row geometry), XCD block swizzle (T1), setprio (T5).
#define M_DIM 8192
#define N_DIM 11008
#define K_DIM 4096
#define BM 256
#define BN 256
#define BK 32
#define NT (K_DIM / BK)   // 128 K-tiles
#define TM (M_DIM / BM)   // 32
#define TN (N_DIM / BN)   // 43
#define NWG (TM * TN)     // 1376 (divisible by 8)

typedef __attribute__((ext_vector_type(8))) short bf16x8;
typedef __attribute__((ext_vector_type(8))) unsigned short u16x8;
typedef __attribute__((ext_vector_type(4))) float f32x4;

__device__ __forceinline__ unsigned short f2bf(float f) {
  union { float f; unsigned u; } v; v.f = f;
  unsigned r = v.u + 0x7FFFu + ((v.u >> 16) & 1u);  // RNE
  return (unsigned short)(r >> 16);
}

__device__ __forceinline__ void gload_lds16(const unsigned short* g, unsigned short* l) {
  __builtin_amdgcn_global_load_lds(
      (const __attribute__((address_space(1))) void*)g,
      (__attribute__((address_space(3))) void*)l, 16, 0, 0);
}

// involution swizzle on byte offset within a 16 KB panel (256 rows x 64 B):
// XOR byte bits 4-5 with row bits 1-2 -> conflict-free ds_read_b128
// (R2/R12-verified: 0 conflicts at this row-stride/lane-group geometry).
__device__ __forceinline__ int swz(int b) { return b ^ ((b >> 3) & 0x30); }

#define BAR() asm volatile("s_barrier" ::: "memory")

// ---- pre-convert kernels (memory-bound) ----
__global__ void cvt_x_kernel(const float* __restrict__ in, unsigned short* __restrict__ o) {
  size_t i = (size_t)blockIdx.x * 256 + threadIdx.x;
  const float4* p = (const float4*)in + i * 2;
  float4 f0 = p[0], f1 = p[1];
  u16x8 v;
  v[0] = f2bf(f0.x); v[1] = f2bf(f0.y); v[2] = f2bf(f0.z); v[3] = f2bf(f0.w);
  v[4] = f2bf(f1.x); v[5] = f2bf(f1.y); v[6] = f2bf(f1.z); v[7] = f2bf(f1.w);
  *((u16x8*)o + i) = v;
}

__global__ void cvt_w_kernel(const float* __restrict__ in, const float* __restrict__ sc,
                             unsigned short* __restrict__ o) {
  size_t i = (size_t)blockIdx.x * 256 + threadIdx.x;
  float s = sc[i >> 9];  // 4096/8 = 512 packs per row
  const float4* p = (const float4*)in + i * 2;
  float4 f0 = p[0], f1 = p[1];
  u16x8 v;
  v[0] = f2bf(f0.x * s); v[1] = f2bf(f0.y * s); v[2] = f2bf(f0.z * s); v[3] = f2bf(f0.w * s);
  v[4] = f2bf(f1.x * s); v[5] = f2bf(f1.y * s); v[6] = f2bf(f1.z * s); v[7] = f2bf(f1.w * s);
  *((u16x8*)o + i) = v;
}

// ---- GEMM ----
__launch_bounds__(512, 4)
__global__ void gemm_kernel(const unsigned short* __restrict__ xb,
                            const unsigned short* __restrict__ wb,
                            const float* __restrict__ bias,
                            float* __restrict__ out) {
  // 2-dbuf of K-tiles: each panel = 256 rows x 32 k bf16 = 16 KB.
  __shared__ unsigned short As[2][8192];  // 32 KB
  __shared__ unsigned short Bs[2][8192];  // 32 KB   (64 KB total -> 2 blocks/CU)

  const int tid = threadIdx.x;
  const int lane = tid & 63;
  const int wave = tid >> 6;
  const int wr = wave >> 2;   // 0..1 -> 128-row half of A
  const int wc = wave & 3;    // 0..3 -> 64-col slice of B

  // T1: XCD-aware swizzle (bijective, NWG%8==0), column-major within chunk.
  int orig = blockIdx.x;
  int wg = (orig & 7) * (NWG / 8) + (orig >> 3);
  int bx = wg / TM;           // N tile 0..42
  int by = wg % TM;           // M tile 0..31
  const int rowBase = by * BM;
  const int colBase = bx * BN;

  f32x4 acc[8][4] = {};

  const int fr = lane & 15;
  const int q16 = (lane >> 4) * 16;  // byte col within 64 B row

  float bias_v[4];
#pragma unroll
  for (int n = 0; n < 4; ++n)
    bias_v[n] = bias[colBase + wc * 64 + n * 16 + fr];

  // staging: panel = 16 KB = 512 threads x 2 x 16 B. Linear LDS dest
  // (wave-uniform base + lane*16), pre-swizzled global source (rule #21).
  const int L0 = tid * 16, L1 = L0 + 8192;
  const int S0 = swz(L0), S1 = swz(L1);
  const int sr0 = S0 >> 6, sc0_ = (S0 & 63) >> 1;
  const int sr1 = S1 >> 6, sc1_ = (S1 & 63) >> 1;  // rows 128..255

  auto stageA = [&](int kt) {
    const unsigned short* src = xb + (size_t)kt * BK;
    unsigned short* dst = &As[kt & 1][0];
    gload_lds16(src + (size_t)(rowBase + sr0) * K_DIM + sc0_, dst + (L0 >> 1));
    gload_lds16(src + (size_t)(rowBase + sr1) * K_DIM + sc1_, dst + (L1 >> 1));
  };
  auto stageB = [&](int kt) {
    const unsigned short* src = wb + (size_t)kt * BK;
    unsigned short* dst = &Bs[kt & 1][0];
    gload_lds16(src + (size_t)(colBase + sr0) * K_DIM + sc0_, dst + (L0 >> 1));
    gload_lds16(src + (size_t)(colBase + sr1) * K_DIM + sc1_, dst + (L1 >> 1));
  };

  bf16x8 aF[4], bF[4];

  auto rdA = [&](int d, int qm) {
    const char* Ab = (const char*)&As[d][0];
#pragma unroll
    for (int mi = 0; mi < 4; ++mi) {
      int b = (wr * 128 + qm * 64 + mi * 16 + fr) * 64 + q16;
      aF[mi] = *(const bf16x8*)(Ab + swz(b));
    }
  };
  auto rdB = [&](int d) {
    const char* Bb = (const char*)&Bs[d][0];
#pragma unroll
    for (int n = 0; n < 4; ++n) {
      int b = (wc * 64 + n * 16 + fr) * 64 + q16;
      bF[n] = *(const bf16x8*)(Bb + swz(b));
    }
  };
  auto mma16 = [&](int qm) {
    __builtin_amdgcn_s_setprio(1);
#pragma unroll
    for (int mi = 0; mi < 4; ++mi)
#pragma unroll
      for (int n = 0; n < 4; ++n)
        acc[qm * 4 + mi][n] = __builtin_amdgcn_mfma_f32_16x16x32_bf16(
            aF[mi], bF[n], acc[qm * 4 + mi][n], 0, 0, 0);
    __builtin_amdgcn_s_setprio(0);
  };

  // prologue: stage K-tile 0 (4 loads/thread), drain, sync.
  stageA(0); stageB(0);
  asm volatile("s_waitcnt vmcnt(0)" ::: "memory");
  BAR();

  // Per K-tile, 2 fine phases:
  //  ph1: rdA(q0) 4 + rdB 4 (8 b128) + stageA(t+1) -> BAR -> 16 MFMA -> BAR
  //  ph2: rdA(q1) 4 + stageB(t+1)                  -> BAR -> 16 MFMA
  //       -> vmcnt(0) -> BAR   (t+1 certified for next ph1's reads)
  // Write-safety: As/Bs[(t+1)&1] was last read in K-tile t-1, whose reads
  // drained before t-1's closing barrier; stages issue after it. The
  // vmcnt(0) bubble is covered by the co-resident second block (TLP).
  for (int t = 0; t < NT; ++t) {
    const int d = t & 1;
    const bool f = (t + 1) < NT;
    // ph1
    rdA(d, 0);
    rdB(d);
    if (f) stageA(t + 1);
    BAR();
    mma16(0);
    BAR();
    // ph2
    rdA(d, 1);
    if (f) stageB(t + 1);
    BAR();
    mma16(1);
    asm volatile("s_waitcnt vmcnt(0)" ::: "memory");
    BAR();
  }

  // epilogue: C/D layout col=lane&15, row=(lane>>4)*4+reg (m89/m91)
  const int r0 = (lane >> 4) * 4;
#pragma unroll
  for (int m = 0; m < 8; ++m) {
#pragma unroll
    for (int r = 0; r < 4; ++r) {
      size_t row = (size_t)(rowBase + wr * 128 + m * 16 + r0 + r);
      float* po = out + row * N_DIM + colBase + wc * 64 + fr;
#pragma unroll
      for (int n = 0; n < 4; ++n)
        po[n * 16] = acc[m][n][r] + bias_v[n];
    }
  }
}

extern "C" void kernel_launch(void* const* d_in, const int* in_sizes, int n_in,
                              void* d_out, int out_size, void* d_ws, size_t ws_size,
                              hipStream_t stream) {
  const float* x = (const float*)d_in[0];   // [8192][4096]
  const float* w = (const float*)d_in[1];   // [11008][4096]
  const float* sc = (const float*)d_in[2];  // [11008]
  const float* bi = (const float*)d_in[3];  // [11008]
  float* out = (float*)d_out;

  const size_t xe = (size_t)M_DIM * K_DIM;
  const size_t we = (size_t)N_DIM * K_DIM;
  unsigned short* xb = (unsigned short*)d_ws;
  unsigned short* wb = xb + xe;

  cvt_x_kernel<<<(unsigned)(xe / 8 / 256), 256, 0, stream>>>(x, xb);
  cvt_w_kernel<<<(unsigned)(we / 8 / 256), 256, 0, stream>>>(w, sc, wb);
  gemm_kernel<<<NWG, 512, 0, stream>>>(xb, wb, bi, out);
}

// Round 17
// 1107.743 us; speedup vs baseline: 5.1008x; 5.1008x over previous
//
#include <hip/hip_runtime.h>

// y[m][n] = sum_k x[m][k] * (w[n][k]*scale[n]) + bias[n]
// M=8192, N=11008, K=4096. fp32 in/out, bf16 MFMA compute.
//
// R17: TLP retry with spill fixed. 128x128 tile, 4 waves (2x2), BK=32,
// 2-dbuf LDS = 32 KB -> 4 blocks/CU (16 waves/CU, 4/SIMD). VGPR working
// set ~88 (R7-measured) < 128 cap of launch_bounds(256,4) -> no spill
// (R16's failure was acc spill at 256² under a 64-reg cap).
// Single-phase K-tile: {8 ds_reads + stageA/B(t+1) -> BAR -> 16 MFMA ->
// vmcnt(0) -> BAR}; drain bubble filled by 3 co-resident blocks (m114).
// Read-side XOR swizzle (0 conflicts, R2/R7/R12), XCD swizzle, setprio.
#define M_DIM 8192
#define N_DIM 11008
#define K_DIM 4096
#define BM 128
#define BN 128
#define BK 32
#define NT (K_DIM / BK)   // 128 K-tiles
#define TM (M_DIM / BM)   // 64
#define TN (N_DIM / BN)   // 86
#define NWG (TM * TN)     // 5504 (divisible by 8)

typedef __attribute__((ext_vector_type(8))) short bf16x8;
typedef __attribute__((ext_vector_type(8))) unsigned short u16x8;
typedef __attribute__((ext_vector_type(4))) float f32x4;

__device__ __forceinline__ unsigned short f2bf(float f) {
  union { float f; unsigned u; } v; v.f = f;
  unsigned r = v.u + 0x7FFFu + ((v.u >> 16) & 1u);  // RNE
  return (unsigned short)(r >> 16);
}

__device__ __forceinline__ void gload_lds16(const unsigned short* g, unsigned short* l) {
  __builtin_amdgcn_global_load_lds(
      (const __attribute__((address_space(1))) void*)g,
      (__attribute__((address_space(3))) void*)l, 16, 0, 0);
}

// involution swizzle on byte offset within an 8 KB panel (128 rows x 64 B):
// XOR byte bits 4-5 with row bits 1-2 -> conflict-free ds_read_b128
// (R2/R7/R12-verified at this row-stride/lane-group geometry).
__device__ __forceinline__ int swz(int b) { return b ^ ((b >> 3) & 0x30); }

#define BAR() asm volatile("s_barrier" ::: "memory")

// ---- pre-convert kernels (memory-bound) ----
__global__ void cvt_x_kernel(const float* __restrict__ in, unsigned short* __restrict__ o) {
  size_t i = (size_t)blockIdx.x * 256 + threadIdx.x;
  const float4* p = (const float4*)in + i * 2;
  float4 f0 = p[0], f1 = p[1];
  u16x8 v;
  v[0] = f2bf(f0.x); v[1] = f2bf(f0.y); v[2] = f2bf(f0.z); v[3] = f2bf(f0.w);
  v[4] = f2bf(f1.x); v[5] = f2bf(f1.y); v[6] = f2bf(f1.z); v[7] = f2bf(f1.w);
  *((u16x8*)o + i) = v;
}

__global__ void cvt_w_kernel(const float* __restrict__ in, const float* __restrict__ sc,
                             unsigned short* __restrict__ o) {
  size_t i = (size_t)blockIdx.x * 256 + threadIdx.x;
  float s = sc[i >> 9];  // 4096/8 = 512 packs per row
  const float4* p = (const float4*)in + i * 2;
  float4 f0 = p[0], f1 = p[1];
  u16x8 v;
  v[0] = f2bf(f0.x * s); v[1] = f2bf(f0.y * s); v[2] = f2bf(f0.z * s); v[3] = f2bf(f0.w * s);
  v[4] = f2bf(f1.x * s); v[5] = f2bf(f1.y * s); v[6] = f2bf(f1.z * s); v[7] = f2bf(f1.w * s);
  *((u16x8*)o + i) = v;
}

// ---- GEMM ----
__launch_bounds__(256, 4)
__global__ void gemm_kernel(const unsigned short* __restrict__ xb,
                            const unsigned short* __restrict__ wb,
                            const float* __restrict__ bias,
                            float* __restrict__ out) {
  // 2-dbuf of K-tiles: each panel = 128 rows x 32 k bf16 = 8 KB.
  __shared__ unsigned short As[2][4096];  // 16 KB
  __shared__ unsigned short Bs[2][4096];  // 16 KB   (32 KB -> 4 blocks/CU)

  const int tid = threadIdx.x;
  const int lane = tid & 63;
  const int wave = tid >> 6;
  const int wr = wave >> 1;   // 0..1 -> 64-row half of A
  const int wc = wave & 1;    // 0..1 -> 64-col half of B

  // T1: XCD-aware swizzle (bijective, NWG%8==0), column-major within chunk.
  int orig = blockIdx.x;
  int wg = (orig & 7) * (NWG / 8) + (orig >> 3);
  int bx = wg / TM;           // N tile 0..85
  int by = wg % TM;           // M tile 0..63
  const int rowBase = by * BM;
  const int colBase = bx * BN;

  f32x4 acc[4][4] = {};

  const int fr = lane & 15;
  const int q16 = (lane >> 4) * 16;  // byte col within 64 B row

  float bias_v[4];
#pragma unroll
  for (int n = 0; n < 4; ++n)
    bias_v[n] = bias[colBase + wc * 64 + n * 16 + fr];

  // staging: panel = 8 KB = 256 threads x 2 x 16 B. Linear LDS dest
  // (wave-uniform base + lane*16), pre-swizzled global source (rule #21).
  const int L0 = tid * 16, L1 = L0 + 4096;
  const int S0 = swz(L0), S1 = swz(L1);
  const int sr0 = S0 >> 6, sc0_ = (S0 & 63) >> 1;
  const int sr1 = S1 >> 6, sc1_ = (S1 & 63) >> 1;  // rows 64..127

  auto stageA = [&](int kt) {
    const unsigned short* src = xb + (size_t)kt * BK;
    unsigned short* dst = &As[kt & 1][0];
    gload_lds16(src + (size_t)(rowBase + sr0) * K_DIM + sc0_, dst + (L0 >> 1));
    gload_lds16(src + (size_t)(rowBase + sr1) * K_DIM + sc1_, dst + (L1 >> 1));
  };
  auto stageB = [&](int kt) {
    const unsigned short* src = wb + (size_t)kt * BK;
    unsigned short* dst = &Bs[kt & 1][0];
    gload_lds16(src + (size_t)(colBase + sr0) * K_DIM + sc0_, dst + (L0 >> 1));
    gload_lds16(src + (size_t)(colBase + sr1) * K_DIM + sc1_, dst + (L1 >> 1));
  };

  bf16x8 aF[4], bF[4];

  auto rdAB = [&](int d) {
    const char* Ab = (const char*)&As[d][0];
    const char* Bb = (const char*)&Bs[d][0];
#pragma unroll
    for (int mi = 0; mi < 4; ++mi) {
      int b = (wr * 64 + mi * 16 + fr) * 64 + q16;
      aF[mi] = *(const bf16x8*)(Ab + swz(b));
    }
#pragma unroll
    for (int n = 0; n < 4; ++n) {
      int b = (wc * 64 + n * 16 + fr) * 64 + q16;
      bF[n] = *(const bf16x8*)(Bb + swz(b));
    }
  };
  auto mma16 = [&]() {
    __builtin_amdgcn_s_setprio(1);
#pragma unroll
    for (int mi = 0; mi < 4; ++mi)
#pragma unroll
      for (int n = 0; n < 4; ++n)
        acc[mi][n] = __builtin_amdgcn_mfma_f32_16x16x32_bf16(
            aF[mi], bF[n], acc[mi][n], 0, 0, 0);
    __builtin_amdgcn_s_setprio(0);
  };

  // prologue: stage K-tile 0 (4 loads/thread), drain, sync.
  stageA(0); stageB(0);
  asm volatile("s_waitcnt vmcnt(0)" ::: "memory");
  BAR();

  // Per K-tile: {8 ds_reads + stage t+1 (4 gloads) -> BAR -> 16 MFMA ->
  // vmcnt(0) -> BAR}. Write-safety: dbuf (t+1)&1 was read at K-tile t-1,
  // whose reads completed before its closing barrier; stage issues after.
  // The per-block drain bubble is covered by 3 co-resident blocks (TLP).
  for (int t = 0; t < NT; ++t) {
    const int d = t & 1;
    const bool f = (t + 1) < NT;
    rdAB(d);
    if (f) { stageA(t + 1); stageB(t + 1); }
    BAR();
    mma16();
    asm volatile("s_waitcnt vmcnt(0)" ::: "memory");
    BAR();
  }

  // epilogue: C/D layout col=lane&15, row=(lane>>4)*4+reg (m89/m91)
  const int r0 = (lane >> 4) * 4;
#pragma unroll
  for (int m = 0; m < 4; ++m) {
#pragma unroll
    for (int r = 0; r < 4; ++r) {
      size_t row = (size_t)(rowBase + wr * 64 + m * 16 + r0 + r);
      float* po = out + row * N_DIM + colBase + wc * 64 + fr;
#pragma unroll
      for (int n = 0; n < 4; ++n)
        po[n * 16] = acc[m][n][r] + bias_v[n];
    }
  }
}

extern "C" void kernel_launch(void* const* d_in, const int* in_sizes, int n_in,
                              void* d_out, int out_size, void* d_ws, size_t ws_size,
                              hipStream_t stream) {
  const float* x = (const float*)d_in[0];   // [8192][4096]
  const float* w = (const float*)d_in[1];   // [11008][4096]
  const float* sc = (const float*)d_in[2];  // [11008]
  const float* bi = (const float*)d_in[3];  // [11008]
  float* out = (float*)d_out;

  const size_t xe = (size_t)M_DIM * K_DIM;
  const size_t we = (size_t)N_DIM * K_DIM;
  unsigned short* xb = (unsigned short*)d_ws;
  unsigned short* wb = xb + xe;

  cvt_x_kernel<<<(unsigned)(xe / 8 / 256), 256, 0, stream>>>(x, xb);
  cvt_w_kernel<<<(unsigned)(we / 8 / 256), 256, 0, stream>>>(w, sc, wb);
  gemm_kernel<<<NWG, 256, 0, stream>>>(xb, wb, bi, out);
}